// Round 10
// baseline (113.946 us; speedup 1.0000x reference)
//
#include <hip/hip_runtime.h>
#include <hip/hip_bf16.h>
#include <math.h>

// Problem constants (fixed by setup_inputs)
#define NB      2      // batch
#define T_IN    12
#define T_OUT_  24
#define O_OUT   12     // T_OUT - T_IN
#define NN      10000  // nodes
#define CC      16     // channels
#define KK      17     // neighbors
#define HH      4      // heads
#define JJ      48     // T_IN * HH
#define PL      24     // planes = NB * T_IN
#define TN      16     // transpose: nodes per block (node-major!)
#define XBLK    (NN / TN)          // 625 transpose blocks
#define SBLK    167                // sigma blocks
#define GW      4      // fused: waves (=nodes) per block
#define GBLK    (NN / GW)          // 2500
#define PSTR    68     // a_s plane stride in floats (16B-aligned, bank-rotating)
#define ANS     (PL * PSTR)        // a_s per-node floats = 1632

typedef float v2f __attribute__((ext_vector_type(2)));

// ---- bf16 helpers ----
__device__ __forceinline__ unsigned int f2bf(float f) {
    union { float f; unsigned int u; } v; v.f = f;
    unsigned int r = v.u + 0x7FFFu + ((v.u >> 16) & 1u);
    return r >> 16;
}
__device__ __forceinline__ float bf_lo(unsigned int u) {
    union { unsigned int u; float f; } v; v.u = u << 16; return v.f;
}
__device__ __forceinline__ float bf_hi(unsigned int u) {
    union { unsigned int u; float f; } v; v.u = u & 0xffff0000u; return v.f;
}
__device__ __forceinline__ v2f bfpair(unsigned int u) {
    v2f r; r.x = bf_lo(u); r.y = bf_hi(u); return r;
}

__device__ __forceinline__ void wave_fence() {
#if __has_builtin(__builtin_amdgcn_wave_barrier)
    __builtin_amdgcn_wave_barrier();   // compiler ordering fence, zero cost
#else
    __syncthreads();
#endif
}

// ---------------- dispatch 1: transpose + passthrough + sigma + W^T ---------
// blocks [0, XBLK): NODE-MAJOR transpose: 16 nodes x all 24 planes. Every
// 768B xt row is produced entirely by ONE block (one XCD) -> full L2 lines,
// no cross-XCD partial-line assembly, good residency for the gather.
// blocks [XBLK, XBLK+SBLK): sigma = max(dists) via signed atomicMax over the
// 0xAA poison (negative int -> below any valid max, no memset needed).
// block XBLK+SBLK: write W^T (J,O) + bias into ws for scalar (SMEM) access.
__global__ __launch_bounds__(256) void setup_kernel(
    const float* __restrict__ x,
    const float* __restrict__ dists, int ndists,
    const float* __restrict__ Wm,
    const float* __restrict__ bias,
    float* __restrict__ out,
    unsigned short* __restrict__ xt,
    float* __restrict__ wt,
    int* __restrict__ sigma_bits)
{
    const int tid = threadIdx.x;
    if (blockIdx.x < XBLK) {
        const int n0 = blockIdx.x * TN;
        // 24 planes x 16 nodes x 4 quads = 1536 float4 items; each wave
        // covers one full plane-segment (1KB contiguous).
        for (int i = tid; i < PL * TN * 4; i += 256) {
            const int p = i >> 6, rem = i & 63, nl = rem >> 2, q = rem & 3;
            const float4 v =
                *(const float4*)(x + ((long)p * NN + n0 + nl) * CC + q * 4);
            const int b = p / T_IN, t = p % T_IN;
            *(float4*)(out + ((long)(b * T_OUT_ + t) * NN + n0 + nl) * CC + q * 4) = v;
            uint2 pk;
            pk.x = f2bf(v.x) | (f2bf(v.y) << 16);
            pk.y = f2bf(v.z) | (f2bf(v.w) << 16);
            ((uint2*)xt)[(long)(n0 + nl) * (PL * 4) + p * 4 + q] = pk;
        }
    } else if (blockIdx.x < XBLK + SBLK) {
        const int sb = blockIdx.x - XBLK;
        float m = 0.0f;
        const int nv4 = ndists >> 2;
        const float4* d4 = (const float4*)dists;
        for (int i = sb * 256 + tid; i < nv4; i += SBLK * 256) {
            float4 v = d4[i];
            m = fmaxf(fmaxf(m, fmaxf(v.x, v.y)), fmaxf(v.z, v.w));
        }
        for (int i = (nv4 << 2) + sb * 256 + tid; i < ndists; i += SBLK * 256)
            m = fmaxf(m, dists[i]);
        #pragma unroll
        for (int off = 32; off > 0; off >>= 1)
            m = fmaxf(m, __shfl_down(m, off, 64));
        __shared__ float sm[4];
        int lane = tid & 63, wid = tid >> 6;
        if (lane == 0) sm[wid] = m;
        __syncthreads();
        if (tid == 0) {
            float mm = fmaxf(fmaxf(sm[0], sm[1]), fmaxf(sm[2], sm[3]));
            atomicMax(sigma_bits, __float_as_int(mm));
        }
    } else {
        // W^T: wt[j*12 + o] = Wm[o*48 + j]; bias appended at wt+576
        for (int i = tid; i < O_OUT * JJ; i += 256)
            wt[i] = Wm[(i % O_OUT) * JJ + (i / O_OUT)];
        if (tid < O_OUT) wt[O_OUT * JJ + tid] = bias[tid];
    }
}

// ---------------- dispatch 2: fused gather + aggregate + shrink + SELU ------
// 256 threads = 4 waves, ONE NODE PER WAVE, wave-private LDS slice, single
// block barrier. Gather: lanes 0-47 cover the node's 768B xt row (dwordx4),
// f32 weights broadcast from LDS, packed-f32 accumulate.
// Shrink: lane = (t-quarter r, channel c); per t: 2 ds_read_b128 (b=0,1),
// W via WAVE-UNIFORM scalar loads (s_load from ws -> zero VALU/DS), y kept
// as v2f over batch -> v_pk_fma; butterfly shfl_xor(16,32) combines the 4
// t-quarters; lane writes o = 3r..3r+2 for both b.
__global__ __launch_bounds__(256) void fused_kernel(
    const unsigned short* __restrict__ xt,
    const int*   __restrict__ nodes,
    const float* __restrict__ dists,
    const int*   __restrict__ sigma_bits,
    const float* __restrict__ wt,
    float* __restrict__ out)
{
    const int tid  = threadIdx.x;
    const int wave = tid >> 6;
    const int lane = tid & 63;
    const int n0   = blockIdx.x * GW;

    __shared__ unsigned lidx[GW * KK];     // xt byte offsets
    __shared__ float4   lwf[GW * KK];      // f32 weights
    __shared__ float    a_s[GW * ANS];     // 25.5 KB f32 agg, wave-private

    // ---- staging (single barrier) ----
    if (tid < GW * KK) {
        const float sigma  = __int_as_float(*sigma_bits);
        const float inv_s2 = 1.0f / (sigma * sigma);
        const int   nd = nodes[n0 * KK + tid];
        const float dd = dists[n0 * KK + tid];
        const float e1 = expf(-dd * dd * inv_s2 * 0.25f);  // w_h = e1^(h+1)
        float w0 = e1, w1 = e1 * e1, w2 = w1 * e1, w3 = w1 * w1;
        if (nd == -1) { w0 = w1 = w2 = w3 = 0.f; }
        if (w0 < 1e-8f) w0 = 0.f;
        if (w1 < 1e-8f) w1 = 0.f;
        if (w2 < 1e-8f) w2 = 0.f;
        if (w3 < 1e-8f) w3 = 0.f;
        lidx[tid] = (unsigned)(((nd < 0) ? 0 : nd) * (PL * CC * 2));
        lwf[tid]  = make_float4(w0, w1, w2, w3);
    }
    __syncthreads();   // the only block-wide barrier

    // ---- gather + aggregate (lanes 0..47; wave-private) ----
    const int rb = wave * KK;
    float* abase = a_s + wave * ANS;
    if (lane < 48) {
        const char* xtb = (const char*)xt;
        v2f acc[HH][4];
        #pragma unroll
        for (int h = 0; h < HH; ++h)
            #pragma unroll
            for (int p = 0; p < 4; ++p) acc[h][p] = (v2f){0.f, 0.f};

        #pragma unroll
        for (int k = 0; k < KK; ++k) {
            const unsigned off = lidx[rb + k];        // wave-uniform broadcast
            const uint4  gv = *(const uint4*)(xtb + off + (lane << 4));
            const float4 wv = lwf[rb + k];            // wave-uniform broadcast
            v2f g[4];
            g[0] = bfpair(gv.x); g[1] = bfpair(gv.y);
            g[2] = bfpair(gv.z); g[3] = bfpair(gv.w);
            #pragma unroll
            for (int p = 0; p < 4; ++p) {
                acc[0][p] += g[p] * wv.x;
                acc[1][p] += g[p] * wv.y;
                acc[2][p] += g[p] * wv.z;
                acc[3][p] += g[p] * wv.w;
            }
        }

        // a_s slice layout: [b][t][c][h] f32, plane stride PSTR=68
        const int plane = lane >> 1;                  // = b*T_IN + t
        const int oct   = lane & 1;                   // channel octet
        float* ap = abase + plane * PSTR + oct * 32;
        #pragma unroll
        for (int j = 0; j < 8; ++j) {
            const int p = j >> 1, e = j & 1;
            *(float4*)(ap + j * 4) = make_float4(acc[0][p][e], acc[1][p][e],
                                                 acc[2][p][e], acc[3][p][e]);
        }
    }
    wave_fence();   // ordering only; same wave reads its own writes below

    // ---- shrink + SELU ----
    const int n = n0 + wave;
    const int c = lane & 15;
    const int r = lane >> 4;                          // t-quarter: t = 3r..3r+2
    v2f y[O_OUT];
    #pragma unroll
    for (int o = 0; o < O_OUT; ++o) y[o] = (v2f){0.f, 0.f};

    #pragma unroll
    for (int tt = 0; tt < 3; ++tt) {
        const int t = r * 3 + tt;
        const float4 a0 = *(const float4*)(abase + t * PSTR + c * 4);
        const float4 a1 = *(const float4*)(abase + (T_IN + t) * PSTR + c * 4);
        const float* wr = wt + t * JJ;                // uniform -> s_load
        #pragma unroll
        for (int h = 0; h < HH; ++h) {
            const v2f av = {((const float*)&a0)[h], ((const float*)&a1)[h]};
            #pragma unroll
            for (int o = 0; o < O_OUT; ++o)
                y[o] += av * wr[h * O_OUT + o];       // v_pk_fma, SGPR weight
        }
    }

    // butterfly-combine the 4 t-quarters (lane bits 4,5)
    #pragma unroll
    for (int o = 0; o < O_OUT; ++o) {
        y[o].x += __shfl_xor(y[o].x, 16, 64);
        y[o].y += __shfl_xor(y[o].y, 16, 64);
        y[o].x += __shfl_xor(y[o].x, 32, 64);
        y[o].y += __shfl_xor(y[o].y, 32, 64);
    }

    const float kScale = 1.0507009873554805f;
    const float kAlpha = 1.6732632423543772f;
    const float* bias_t = wt + O_OUT * JJ;            // uniform -> s_load
    #pragma unroll
    for (int i = 0; i < 3; ++i) {
        const int o = r * 3 + i;
        const float bv = bias_t[o];
        #pragma unroll
        for (int b = 0; b < NB; ++b) {
            float v = ((b == 0) ? y[o].x : y[o].y) + bv;
            v = (v > 0.0f) ? kScale * v : kScale * kAlpha * (__expf(v) - 1.0f);
            out[((long)(b * T_OUT_ + T_IN + o) * NN + n) * CC + c] = v;
        }
    }
}

extern "C" void kernel_launch(void* const* d_in, const int* in_sizes, int n_in,
                              void* d_out, int out_size, void* d_ws, size_t ws_size,
                              hipStream_t stream) {
    const float* x     = (const float*)d_in[0];
    const int*   nodes = (const int*)  d_in[1];
    const float* dists = (const float*)d_in[2];
    const float* Wm    = (const float*)d_in[3];
    const float* bias  = (const float*)d_in[4];
    float* out = (float*)d_out;

    // ws layout: [0,4)=sigma | 64: wt (576+12 f32) | 4096: xt (7.68 MB bf16)
    char* ws = (char*)d_ws;
    int*            sigma_bits = (int*)ws;
    float*          wt         = (float*)(ws + 64);
    unsigned short* xt         = (unsigned short*)(ws + 4096);

    const int ndists = in_sizes[2];  // N*K = 170000
    setup_kernel<<<XBLK + SBLK + 1, 256, 0, stream>>>(
        x, dists, ndists, Wm, bias, out, xt, wt, sigma_bits);
    fused_kernel<<<GBLK, 256, 0, stream>>>(xt, nodes, dists, sigma_bits,
                                           wt, out);
}

// Round 11
// 112.379 us; speedup vs baseline: 1.0139x; 1.0139x over previous
//
#include <hip/hip_runtime.h>
#include <hip/hip_bf16.h>
#include <math.h>

// Problem constants (fixed by setup_inputs)
#define NB      2      // batch
#define T_IN    12
#define T_OUT_  24
#define O_OUT   12     // T_OUT - T_IN
#define NN      10000  // nodes
#define CC      16     // channels
#define KK      17     // neighbors
#define HH      4      // heads
#define JJ      48     // T_IN * HH
#define PL      24     // planes = NB * T_IN
#define XCHN    40     // transpose: node-chunks per plane
#define CHN     250    // nodes per transpose chunk
#define XBLK    (PL * XCHN)        // 960 transpose blocks
#define SBLK    167                // sigma blocks
#define GW      4      // fused: waves (=nodes) per block
#define GBLK    (NN / GW)          // 2500
#define PSTR    68     // a_s plane stride in floats (16B-aligned, bank-rotating)
#define ANS     (PL * PSTR)        // a_s per-node floats = 1632 (6528 B)

typedef float v2f __attribute__((ext_vector_type(2)));

// ---- bf16 helpers ----
__device__ __forceinline__ unsigned int f2bf(float f) {
    union { float f; unsigned int u; } v; v.f = f;
    unsigned int r = v.u + 0x7FFFu + ((v.u >> 16) & 1u);
    return r >> 16;
}
__device__ __forceinline__ float bf_lo(unsigned int u) {
    union { unsigned int u; float f; } v; v.u = u << 16; return v.f;
}
__device__ __forceinline__ float bf_hi(unsigned int u) {
    union { unsigned int u; float f; } v; v.u = u & 0xffff0000u; return v.f;
}
__device__ __forceinline__ v2f bfpair(unsigned int u) {
    v2f r;
    r.x = bf_lo(u);
    r.y = bf_hi(u);
    return r;
}

__device__ __forceinline__ void wave_fence() {
#if __has_builtin(__builtin_amdgcn_wave_barrier)
    __builtin_amdgcn_wave_barrier();   // compiler ordering fence, zero cost
#else
    __syncthreads();
#endif
}

// ---------------- dispatch 1: transpose + passthrough + sigma ---------------
// blocks [0, XBLK): plane p = bid/40, chunk = bid%40 (250 nodes). Streams
// contiguous 4KB runs (load x, store out passthrough, scatter-pack xt).
// blocks [XBLK, XBLK+SBLK): sigma = max(dists), signed atomicMax over the
// 0xAA poison (negative int) -- no memset dispatch needed.
__global__ __launch_bounds__(256) void setup_kernel(
    const float* __restrict__ x,
    const float* __restrict__ dists, int ndists,
    float* __restrict__ out,
    unsigned short* __restrict__ xt,
    int* __restrict__ sigma_bits)
{
    const int tid = threadIdx.x;
    if (blockIdx.x < XBLK) {
        const int p  = blockIdx.x / XCHN;      // uniform per block
        const int ch = blockIdx.x % XCHN;
        const int b = p / T_IN, t = p % T_IN;
        const int n0 = ch * CHN;
        const float* xp = x + (long)(p * NN + n0) * CC;
        float* op = out + (long)((b * T_OUT_ + t) * NN + n0) * CC;
        uint2* xtp = (uint2*)xt + (long)n0 * (PL * 4) + p * 4;
        // 250 nodes x 4 quads = 1000 float4 items
        for (int i = tid; i < CHN * 4; i += 256) {
            const int nl = i >> 2, q = i & 3;
            const float4 v = *(const float4*)(xp + i * 4);
            *(float4*)(op + i * 4) = v;
            uint2 pk;
            pk.x = f2bf(v.x) | (f2bf(v.y) << 16);
            pk.y = f2bf(v.z) | (f2bf(v.w) << 16);
            xtp[(long)nl * (PL * 4) + q] = pk;
        }
    } else {
        const int sb = blockIdx.x - XBLK;
        float m = 0.0f;
        const int nv4 = ndists >> 2;
        const float4* d4 = (const float4*)dists;
        for (int i = sb * 256 + tid; i < nv4; i += SBLK * 256) {
            float4 v = d4[i];
            m = fmaxf(fmaxf(m, fmaxf(v.x, v.y)), fmaxf(v.z, v.w));
        }
        for (int i = (nv4 << 2) + sb * 256 + tid; i < ndists; i += SBLK * 256)
            m = fmaxf(m, dists[i]);
        #pragma unroll
        for (int off = 32; off > 0; off >>= 1)
            m = fmaxf(m, __shfl_down(m, off, 64));
        __shared__ float sm[4];
        int lane = tid & 63, wid = tid >> 6;
        if (lane == 0) sm[wid] = m;
        __syncthreads();
        if (tid == 0) {
            float mm = fmaxf(fmaxf(sm[0], sm[1]), fmaxf(sm[2], sm[3]));
            atomicMax(sigma_bits, __float_as_int(mm));
        }
    }
}

// ---------------- dispatch 2: fused gather + aggregate + shrink + SELU ------
// 256 threads = 4 waves, ONE NODE PER WAVE, wave-private LDS slice, single
// block barrier. Gather: lanes 0-47 cover the node's 768B xt row; all 17
// dwordx4 gathers preloaded into registers (17-deep MLP). Aggregation in
// packed float2 (v_pk_fma_f32). This kernel is at the gather-bandwidth bound:
// 130 MB of random 768B rows through L2/L3 at ~5 TB/s effective.
__global__ __launch_bounds__(256) void fused_kernel(
    const unsigned short* __restrict__ xt,
    const int*   __restrict__ nodes,
    const float* __restrict__ dists,
    const int*   __restrict__ sigma_bits,
    const float* __restrict__ Wm,
    const float* __restrict__ bias,
    float* __restrict__ out)
{
    const int tid  = threadIdx.x;
    const int wave = tid >> 6;
    const int lane = tid & 63;
    const int n0   = blockIdx.x * GW;

    __shared__ float    W_s[O_OUT * JJ];   // 2.25 KB
    __shared__ float    b_s[O_OUT];
    __shared__ unsigned lidx[GW * KK];     // xt byte offsets
    __shared__ uint2    lw2[GW * KK];      // packed bf16 weight pairs
    __shared__ float    a_s[GW * ANS];     // 25.5 KB f32 agg, wave-private

    // ---- cooperative staging (single barrier) ----
    for (int i = tid; i < O_OUT * JJ; i += 256) W_s[i] = Wm[i];
    if (tid < O_OUT) b_s[tid] = bias[tid];
    if (tid < GW * KK) {
        const float sigma  = __int_as_float(*sigma_bits);
        const float inv_s2 = 1.0f / (sigma * sigma);
        const int   nd = nodes[n0 * KK + tid];
        const float dd = dists[n0 * KK + tid];
        const float e1 = expf(-dd * dd * inv_s2 * 0.25f);  // w_h = e1^(h+1)
        float w0 = e1, w1 = e1 * e1, w2 = w1 * e1, w3 = w1 * w1;
        if (nd == -1) { w0 = w1 = w2 = w3 = 0.f; }
        if (w0 < 1e-8f) w0 = 0.f;
        if (w1 < 1e-8f) w1 = 0.f;
        if (w2 < 1e-8f) w2 = 0.f;
        if (w3 < 1e-8f) w3 = 0.f;
        lidx[tid] = (unsigned)(((nd < 0) ? 0 : nd) * (PL * CC * 2));
        lw2[tid]  = make_uint2(f2bf(w0) | (f2bf(w1) << 16),
                               f2bf(w2) | (f2bf(w3) << 16));
    }
    __syncthreads();   // the only block-wide barrier

    // ---- gather + aggregate (lanes 0..47; wave-private) ----
    const int rb = wave * KK;
    float* abase = a_s + wave * ANS;
    if (lane < 48) {
        const char* xtb = (const char*)xt;
        // preload ALL 17 gathers -> 17 outstanding vmem loads per wave
        uint4 gv[KK];
        #pragma unroll
        for (int k = 0; k < KK; ++k)
            gv[k] = *(const uint4*)(xtb + lidx[rb + k] + (lane << 4));

        v2f acc[HH][4];
        #pragma unroll
        for (int h = 0; h < HH; ++h)
            #pragma unroll
            for (int p = 0; p < 4; ++p) acc[h][p] = (v2f){0.f, 0.f};

        #pragma unroll
        for (int k = 0; k < KK; ++k) {
            const uint2 wp = lw2[rb + k];            // wave-uniform broadcast
            const v2f vw0 = {bf_lo(wp.x), bf_lo(wp.x)};
            const v2f vw1 = {bf_hi(wp.x), bf_hi(wp.x)};
            const v2f vw2 = {bf_lo(wp.y), bf_lo(wp.y)};
            const v2f vw3 = {bf_hi(wp.y), bf_hi(wp.y)};
            v2f g[4];
            g[0] = bfpair(gv[k].x);
            g[1] = bfpair(gv[k].y);
            g[2] = bfpair(gv[k].z);
            g[3] = bfpair(gv[k].w);
            #pragma unroll
            for (int p = 0; p < 4; ++p) {
                acc[0][p] += g[p] * vw0;
                acc[1][p] += g[p] * vw1;
                acc[2][p] += g[p] * vw2;
                acc[3][p] += g[p] * vw3;
            }
        }

        // a_s slice layout: [plane][c][h] f32, plane stride PSTR=68
        const int plane = lane >> 1;
        const int oct   = lane & 1;                  // channel octet
        float* ap = abase + plane * PSTR + oct * 32;
        #pragma unroll
        for (int j = 0; j < 8; ++j) {
            const int p = j >> 1, e = j & 1;
            *(float4*)(ap + j * 4) = make_float4(acc[0][p][e], acc[1][p][e],
                                                 acc[2][p][e], acc[3][p][e]);
        }
    }
    wave_fence();   // ordering only; same wave reads its own writes below

    // ---- shrink + SELU: lane = (c, o-quarter); 6 outputs per lane ----
    const float kScale = 1.0507009873554805f;
    const float kAlpha = 1.6732632423543772f;
    const int n = n0 + wave;
    const int c = lane & 15;
    const int d = lane >> 4;                         // o-quarter: o = 3d..3d+2
    float y[3][NB];
    #pragma unroll
    for (int i = 0; i < 3; ++i) {
        const float bv = b_s[d * 3 + i];
        y[i][0] = bv; y[i][1] = bv;
    }
    #pragma unroll
    for (int t = 0; t < T_IN; ++t) {
        const float4 a0 = *(const float4*)(abase + t * PSTR + c * 4);
        const float4 a1 = *(const float4*)(abase + (T_IN + t) * PSTR + c * 4);
        #pragma unroll
        for (int i = 0; i < 3; ++i) {
            const float4 wv = *(const float4*)(W_s + (d * 3 + i) * JJ + t * 4);
            y[i][0] += a0.x * wv.x + a0.y * wv.y + a0.z * wv.z + a0.w * wv.w;
            y[i][1] += a1.x * wv.x + a1.y * wv.y + a1.z * wv.z + a1.w * wv.w;
        }
    }
    #pragma unroll
    for (int i = 0; i < 3; ++i)
        #pragma unroll
        for (int b = 0; b < NB; ++b) {
            float v = y[i][b];
            v = (v > 0.0f) ? kScale * v : kScale * kAlpha * (__expf(v) - 1.0f);
            const int o = d * 3 + i;
            out[((long)(b * T_OUT_ + T_IN + o) * NN + n) * CC + c] = v;
        }
}

extern "C" void kernel_launch(void* const* d_in, const int* in_sizes, int n_in,
                              void* d_out, int out_size, void* d_ws, size_t ws_size,
                              hipStream_t stream) {
    const float* x     = (const float*)d_in[0];
    const int*   nodes = (const int*)  d_in[1];
    const float* dists = (const float*)d_in[2];
    const float* Wm    = (const float*)d_in[3];
    const float* bias  = (const float*)d_in[4];
    float* out = (float*)d_out;

    // ws layout: [0,4)=sigma (int bits) | 1024: xt (NN x 24 x 16 bf16, 7.68 MB)
    char* ws = (char*)d_ws;
    int*            sigma_bits = (int*)ws;
    unsigned short* xt         = (unsigned short*)(ws + 1024);

    const int ndists = in_sizes[2];  // N*K = 170000
    setup_kernel<<<XBLK + SBLK, 256, 0, stream>>>(x, dists, ndists, out, xt,
                                                  sigma_bits);
    fused_kernel<<<GBLK, 256, 0, stream>>>(xt, nodes, dists, sigma_bits,
                                           Wm, bias, out);
}